// Round 5
// baseline (290.701 us; speedup 1.0000x reference)
//
#include <hip/hip_runtime.h>
#include <stdint.h>
#include <stddef.h>

#define DEVINL __device__ __forceinline__

typedef unsigned short u16;
typedef unsigned int u32;
typedef __attribute__((ext_vector_type(8))) short short8;
typedef __attribute__((ext_vector_type(4))) float f32x4;
typedef __attribute__((ext_vector_type(4))) u32 u32x4;
typedef __attribute__((ext_vector_type(2))) u32 u32x2;

// log2(e)/8 : folded into W_q / b_q so flash's exp2 needs no multiply
#define QSCALE 0.18033688011112042f

// ---------- helpers ----------
DEVINL u16 f2bf(float f) {
    u32 u = __builtin_bit_cast(u32, f);
    u32 r = (u + 0x7fffu + ((u >> 16) & 1u)) >> 16;   // RNE
    return (u16)r;
}

DEVINL void gld_lds16(const void* g, void* l) {
    __builtin_amdgcn_global_load_lds(
        (__attribute__((address_space(1))) u32*)(uintptr_t)g,
        (__attribute__((address_space(3))) u32*)l, 16, 0, 0);
}

// pack two fp32 -> bf16x2 by truncation (bias cancels: denominator sums the same bf16 P)
DEVINL u32 pack_bf16_trunc(float lo, float hi) {
    return __builtin_amdgcn_perm(__builtin_bit_cast(u32, hi),
                                 __builtin_bit_cast(u32, lo), 0x07060302u);
}

// ---------- fused input prep: casts + scale folding, one launch ----------
__global__ void prep_inputs(const float* __restrict__ x, const float* __restrict__ wqkv,
                            const float* __restrict__ bqkv, const float* __restrict__ wo,
                            u16* __restrict__ xb, u16* __restrict__ wqb,
                            u16* __restrict__ wob, float* __restrict__ bsc) {
    int blk = blockIdx.x;
    if (blk < 6144) {
        const float* src; u16* dst; int base; bool qscale = false;
        if (blk < 4096)      { src = x;    dst = xb;  base = blk; }
        else if (blk < 5632) { src = wqkv; dst = wqb; base = blk - 4096; qscale = true; }
        else                 { src = wo;   dst = wob; base = blk - 5632; }
        int i = (base * 256 + threadIdx.x) * 8;
        float sc = 1.0f;
        if (qscale) { int row = i >> 10; if ((row % 192) < 64) sc = QSCALE; }
        float4 a = *(const float4*)(src + i);
        float4 c = *(const float4*)(src + i + 4);
        union { u16 s[8]; u32x4 v; } t;
        t.s[0] = f2bf(a.x * sc); t.s[1] = f2bf(a.y * sc); t.s[2] = f2bf(a.z * sc); t.s[3] = f2bf(a.w * sc);
        t.s[4] = f2bf(c.x * sc); t.s[5] = f2bf(c.y * sc); t.s[6] = f2bf(c.z * sc); t.s[7] = f2bf(c.w * sc);
        *(u32x4*)(dst + i) = t.v;
    } else {
        int i = (blk - 6144) * 256 + threadIdx.x;   // 0..3071
        float sc = ((i % 192) < 64) ? QSCALE : 1.0f;
        bsc[i] = bqkv[i] * sc;
    }
}

// ---------- QKV GEMM  qkv[M,3072] = x[M,K] * w_qkv[3072,K]^T + b ----------
// V-section columns written transposed straight to vt[bh][d][s].
__global__ void gemm_qkv(const u16* __restrict__ A, const u16* __restrict__ Bm,
                         const float* __restrict__ bias, u16* __restrict__ qkvb,
                         u16* __restrict__ vtb) {
    const int K = 1024, N = 3072;
    __shared__ u16 As[128 * 32];
    __shared__ u16 Bs[128 * 32];
    const int tid = threadIdx.x;
    const int lane = tid & 63;
    const int wv = tid >> 6, wr = wv >> 1, wc = wv & 1;
    const int l15 = lane & 15, quad = lane >> 4;
    const int m0 = blockIdx.y * 128, n0 = blockIdx.x * 128;

    f32x4 acc[4][4];
#pragma unroll
    for (int i = 0; i < 4; i++)
#pragma unroll
        for (int j = 0; j < 4; j++) acc[i][j] = (f32x4){0.f, 0.f, 0.f, 0.f};

    const u16* Ab = A + (size_t)m0 * K;
    const u16* Bb = Bm + (size_t)n0 * K;
    const int srow = tid >> 2;
    const int sc8 = (tid & 3) * 8;

    for (int k0 = 0; k0 < K; k0 += 32) {
#pragma unroll
        for (int i = 0; i < 2; i++) {
            int row = i * 64 + srow;
            gld_lds16(Ab + (size_t)row * K + k0 + sc8, (char*)As + (size_t)(i * 256 + tid) * 16);
            gld_lds16(Bb + (size_t)row * K + k0 + sc8, (char*)Bs + (size_t)(i * 256 + tid) * 16);
        }
        __syncthreads();
        short8 af[4], bf8[4];
#pragma unroll
        for (int mi = 0; mi < 4; mi++)
            af[mi] = *(const short8*)(As + (wr * 64 + mi * 16 + l15) * 32 + quad * 8);
#pragma unroll
        for (int ni = 0; ni < 4; ni++)
            bf8[ni] = *(const short8*)(Bs + (wc * 64 + ni * 16 + l15) * 32 + quad * 8);
#pragma unroll
        for (int mi = 0; mi < 4; mi++)
#pragma unroll
            for (int ni = 0; ni < 4; ni++)
                acc[mi][ni] = __builtin_amdgcn_mfma_f32_16x16x32_bf16(af[mi], bf8[ni], acc[mi][ni], 0, 0, 0);
        __syncthreads();
    }

#pragma unroll
    for (int mi = 0; mi < 4; mi++) {
        int row_b = m0 + wr * 64 + mi * 16 + quad * 4;
#pragma unroll
        for (int ni = 0; ni < 4; ni++) {
            int c0 = n0 + wc * 64 + ni * 16;          // group base (16-aligned)
            int sec0 = c0 % 192;                       // section offset, wave-uniform
            float bv = bias[c0 + l15];
            float v0 = acc[mi][ni][0] + bv;
            float v1 = acc[mi][ni][1] + bv;
            float v2 = acc[mi][ni][2] + bv;
            float v3 = acc[mi][ni][3] + bv;
            if (sec0 >= 128) {
                int hh = c0 / 192;
                int b = row_b >> 11;
                int s = row_b & 2047;
                int d = sec0 - 128 + l15;
                u32 lo = (u32)f2bf(v0) | ((u32)f2bf(v1) << 16);
                u32 hi = (u32)f2bf(v2) | ((u32)f2bf(v3) << 16);
                *(u32x2*)(vtb + ((size_t)((b * 16 + hh) * 64 + d)) * 2048 + s) = (u32x2){lo, hi};
            } else {
                int col = c0 + l15;
                qkvb[(size_t)(row_b + 0) * N + col] = f2bf(v0);
                qkvb[(size_t)(row_b + 1) * N + col] = f2bf(v1);
                qkvb[(size_t)(row_b + 2) * N + col] = f2bf(v2);
                qkvb[(size_t)(row_b + 3) * N + col] = f2bf(v3);
            }
        }
    }
}

// ---------- out GEMM  out[M,1024] = vals2[M,K] * w_o[1024,K]^T + b_o ----------
__global__ void gemm_out(const u16* __restrict__ A, const u16* __restrict__ Bm,
                         const float* __restrict__ bias, float* __restrict__ C) {
    const int K = 1024, N = 1024;
    __shared__ u16 As[128 * 32];
    __shared__ u16 Bs[64 * 32];
    const int tid = threadIdx.x;
    const int lane = tid & 63;
    const int wv = tid >> 6, wr = wv >> 1, wc = wv & 1;
    const int l15 = lane & 15, quad = lane >> 4;
    const int m0 = blockIdx.y * 128, n0 = blockIdx.x * 64;

    f32x4 acc[4][2];
#pragma unroll
    for (int i = 0; i < 4; i++)
#pragma unroll
        for (int j = 0; j < 2; j++) acc[i][j] = (f32x4){0.f, 0.f, 0.f, 0.f};

    const u16* Ab = A + (size_t)m0 * K;
    const u16* Bb = Bm + (size_t)n0 * K;
    const int srow = tid >> 2;
    const int sc8 = (tid & 3) * 8;

    for (int k0 = 0; k0 < K; k0 += 32) {
#pragma unroll
        for (int i = 0; i < 2; i++)
            gld_lds16(Ab + (size_t)(i * 64 + srow) * K + k0 + sc8, (char*)As + (size_t)(i * 256 + tid) * 16);
        gld_lds16(Bb + (size_t)srow * K + k0 + sc8, (char*)Bs + (size_t)tid * 16);
        __syncthreads();
        short8 af[4], bf8[2];
#pragma unroll
        for (int mi = 0; mi < 4; mi++)
            af[mi] = *(const short8*)(As + (wr * 64 + mi * 16 + l15) * 32 + quad * 8);
#pragma unroll
        for (int ni = 0; ni < 2; ni++)
            bf8[ni] = *(const short8*)(Bs + (wc * 32 + ni * 16 + l15) * 32 + quad * 8);
#pragma unroll
        for (int mi = 0; mi < 4; mi++)
#pragma unroll
            for (int ni = 0; ni < 2; ni++)
                acc[mi][ni] = __builtin_amdgcn_mfma_f32_16x16x32_bf16(af[mi], bf8[ni], acc[mi][ni], 0, 0, 0);
        __syncthreads();
    }

#pragma unroll
    for (int mi = 0; mi < 4; mi++) {
        int row_b = m0 + wr * 64 + mi * 16 + quad * 4;
#pragma unroll
        for (int ni = 0; ni < 2; ni++) {
            int col = n0 + wc * 32 + ni * 16 + l15;
            float bv = bias[col];
#pragma unroll
            for (int r = 0; r < 4; r++)
                C[(size_t)(row_b + r) * N + col] = acc[mi][ni][r] + bv;
        }
    }
}

// ---------- flash attention v4: 2x2 (q-half, key-half) wave split ----------
// Block = 128 q rows x 128-key staged tiles. Wave (qw,kw) computes its 64 q
// x 64 keys: K/V fragments read by 2 waves instead of 4 (halved LDS traffic).
// No online max (scale pre-folded); denominator via ones-MFMA; O/sum partials
// over key-halves merged once per block through LDS (purely additive).
__launch_bounds__(256, 2)
__global__ void flash_attn(const u16* __restrict__ qkv, const u16* __restrict__ vt,
                           u16* __restrict__ vals2) {
    // SM layout (u16 units): Ks [0,9216) 128x72 ; Vts [9216,17920) 64x136 ;
    // Ps [17920,36352) 4 waves x 64x72. Epilogue reuses: O-partials (f32) at
    // [0,32KB), sum-partials (f32) at Ps base.
    __shared__ u16 SM[36352];
    u16* Ks  = SM;
    u16* Vts = SM + 9216;
    u16* Ps  = SM + 17920;

    const int tid = threadIdx.x;
    const int lane = tid & 63, wv = tid >> 6;
    const int qw = wv >> 1, kw = wv & 1;
    const int l15 = lane & 15, quad = lane >> 4;
    const int s0 = blockIdx.x * 128;
    const int bh = blockIdx.y, b = bh >> 4, h = bh & 15;

    // Q fragments in registers: this wave's 64 q rows (pre-scaled by log2e/8)
    short8 qf[4][2];
    const u16* qbase = qkv + (size_t)(b * 2048 + s0 + qw * 64) * 3072 + h * 192;
#pragma unroll
    for (int qi = 0; qi < 4; qi++)
#pragma unroll
        for (int ks = 0; ks < 2; ks++)
            qf[qi][ks] = *(const short8*)(qbase + (size_t)(qi * 16 + l15) * 3072 + ks * 32 + quad * 8);

    f32x4 o_acc[4][4];
    f32x4 sum_acc[4];
#pragma unroll
    for (int qi = 0; qi < 4; qi++) {
        sum_acc[qi] = (f32x4){0.f, 0.f, 0.f, 0.f};
#pragma unroll
        for (int nd = 0; nd < 4; nd++) o_acc[qi][nd] = (f32x4){0.f, 0.f, 0.f, 0.f};
    }

    const u16* kg = qkv + (size_t)(b * 2048) * 3072 + h * 192 + 64;
    const u16* vg = vt + (size_t)bh * 64 * 2048;

    // staging maps: K 128 rows x 64 d (row=t>>1, half=t&1, 64 B each);
    //               Vt 64 rows x 128 keys (row=t>>2, q4=t&3, 64 B each)
    const int krow = tid >> 1, khalf = (tid & 1) * 32;
    const int vrow = tid >> 2, vq4 = (tid & 3) * 32;

    u16* Pw = Ps + wv * 64 * 72;
    const short8 ones = (short8){0x3F80, 0x3F80, 0x3F80, 0x3F80, 0x3F80, 0x3F80, 0x3F80, 0x3F80};

    for (int kb = 0; kb < 2048; kb += 128) {
        __syncthreads();
        // stage K (128 keys x 64 d, pad 72) and Vt (64 d x 128 keys, pad 136)
        const u16* kgr = kg + (size_t)(kb + krow) * 3072 + khalf;
        const u16* vgr = vg + (size_t)vrow * 2048 + kb + vq4;
        u32x4 ka = *(const u32x4*)(kgr);
        u32x4 kb4 = *(const u32x4*)(kgr + 8);
        u32x4 kc = *(const u32x4*)(kgr + 16);
        u32x4 kd = *(const u32x4*)(kgr + 24);
        u32x4 va = *(const u32x4*)(vgr);
        u32x4 vb4 = *(const u32x4*)(vgr + 8);
        u32x4 vc = *(const u32x4*)(vgr + 16);
        u32x4 vd = *(const u32x4*)(vgr + 24);
        u16* kdst = Ks + krow * 72 + khalf;
        u16* vdst = Vts + vrow * 136 + vq4;
        *(u32x4*)(kdst) = ka;  *(u32x4*)(kdst + 8) = kb4;
        *(u32x4*)(kdst + 16) = kc; *(u32x4*)(kdst + 24) = kd;
        *(u32x4*)(vdst) = va;  *(u32x4*)(vdst + 8) = vb4;
        *(u32x4*)(vdst + 16) = vc; *(u32x4*)(vdst + 24) = vd;
        __syncthreads();

        // S^T = K * Q^T over this wave's 64 keys x 64 q
        // s_acc[ki][qi]: key = kw*64 + ki*16 + quad*4 + r, q = qw*64 + qi*16 + l15
        f32x4 s_acc[4][4];
#pragma unroll
        for (int ki = 0; ki < 4; ki++)
#pragma unroll
            for (int qi = 0; qi < 4; qi++) s_acc[ki][qi] = (f32x4){0.f, 0.f, 0.f, 0.f};
#pragma unroll
        for (int ki = 0; ki < 4; ki++) {
#pragma unroll
            for (int ks = 0; ks < 2; ks++) {
                short8 kf = *(const short8*)(Ks + (kw * 64 + ki * 16 + l15) * 72 + ks * 32 + quad * 8);
#pragma unroll
                for (int qi = 0; qi < 4; qi++)
                    s_acc[ki][qi] = __builtin_amdgcn_mfma_f32_16x16x32_bf16(kf, qf[qi][ks], s_acc[ki][qi], 0, 0, 0);
            }
        }

        // P = exp2(S^T) -> truncate-pack bf16 -> wave-private LDS (A-layout [q][key])
#pragma unroll
        for (int ki = 0; ki < 4; ki++)
#pragma unroll
            for (int qi = 0; qi < 4; qi++) {
                float p0 = __builtin_amdgcn_exp2f(s_acc[ki][qi][0]);
                float p1 = __builtin_amdgcn_exp2f(s_acc[ki][qi][1]);
                float p2 = __builtin_amdgcn_exp2f(s_acc[ki][qi][2]);
                float p3 = __builtin_amdgcn_exp2f(s_acc[ki][qi][3]);
                u32x2 pk = (u32x2){pack_bf16_trunc(p0, p1), pack_bf16_trunc(p2, p3)};
                *(u32x2*)(Pw + (qi * 16 + l15) * 72 + ki * 16 + quad * 4) = pk;
            }

        // PV over 2 chunks of 32 keys; denominator via ones-column MFMA
#pragma unroll
        for (int c = 0; c < 2; c++) {
            short8 ap[4];
#pragma unroll
            for (int qi = 0; qi < 4; qi++)
                ap[qi] = *(const short8*)(Pw + (qi * 16 + l15) * 72 + c * 32 + quad * 8);
#pragma unroll
            for (int qi = 0; qi < 4; qi++)
                sum_acc[qi] = __builtin_amdgcn_mfma_f32_16x16x32_bf16(ap[qi], ones, sum_acc[qi], 0, 0, 0);
#pragma unroll
            for (int nd = 0; nd < 4; nd++) {
                short8 bv = *(const short8*)(Vts + (nd * 16 + l15) * 136 + kw * 64 + c * 32 + quad * 8);
#pragma unroll
                for (int qi = 0; qi < 4; qi++)
                    o_acc[qi][nd] = __builtin_amdgcn_mfma_f32_16x16x32_bf16(ap[qi], bv, o_acc[qi][nd], 0, 0, 0);
            }
        }
    }

    // merge key-half partials (additive: no max rescaling), then epilogue.
    float* Ored = (float*)SM;             // 2 qw x 16 frags x 64 lanes x f32x4 = 32 KB
    float* Sred = (float*)Ps;             // 2 qw x 4 frags x 64 lanes x f32x4 = 8 KB
    __syncthreads();
    if (kw == 1) {
#pragma unroll
        for (int qi = 0; qi < 4; qi++) {
#pragma unroll
            for (int nd = 0; nd < 4; nd++)
                *(f32x4*)(Ored + (((qw * 16 + qi * 4 + nd) * 64) + lane) * 4) = o_acc[qi][nd];
            *(f32x4*)(Sred + (((qw * 4 + qi) * 64) + lane) * 4) = sum_acc[qi];
        }
    }
    __syncthreads();
    if (kw == 0) {
#pragma unroll
        for (int qi = 0; qi < 4; qi++) {
            f32x4 sp = *(const f32x4*)(Sred + (((qw * 4 + qi) * 64) + lane) * 4);
            f32x4 inv;
#pragma unroll
            for (int r = 0; r < 4; r++) inv[r] = 1.0f / (sum_acc[qi][r] + sp[r]);
#pragma unroll
            for (int nd = 0; nd < 4; nd++) {
                f32x4 op = *(const f32x4*)(Ored + (((qw * 16 + qi * 4 + nd) * 64) + lane) * 4);
                int d = nd * 16 + l15;
#pragma unroll
                for (int r = 0; r < 4; r++) {
                    int s = s0 + qw * 64 + qi * 16 + quad * 4 + r;
                    size_t row2 = (size_t)(b * 2048 + h * 128 + (s >> 4));
                    int col2 = ((s & 15) << 6) + d;
                    vals2[row2 * 1024 + col2] = f2bf((o_acc[qi][nd][r] + op[r]) * inv[r]);
                }
            }
        }
    }
}

// ---------- launch ----------
extern "C" void kernel_launch(void* const* d_in, const int* in_sizes, int n_in,
                              void* d_out, int out_size, void* d_ws, size_t ws_size,
                              hipStream_t stream) {
    (void)in_sizes; (void)n_in; (void)out_size; (void)ws_size;
    const float* x      = (const float*)d_in[0];   // (4,2048,1024)
    const float* w_qkv  = (const float*)d_in[1];   // (3072,1024)
    const float* b_qkv  = (const float*)d_in[2];   // (3072,)
    const float* w_o    = (const float*)d_in[3];   // (1024,1024)
    const float* b_o    = (const float*)d_in[4];   // (1024,)
    float* out = (float*)d_out;

    char* ws = (char*)d_ws;
    u16* xb   = (u16*)(ws);                          // 16 MB  x bf16 (8192x1024)
    u16* wqb  = (u16*)(ws + 16777216);               // 6 MB   w_qkv bf16 (Q rows pre-scaled)
    u16* wob  = (u16*)(ws + 23068672);               // 2 MB   w_o bf16
    u16* qkvb = (u16*)(ws + 25165824);               // 48 MB  qkv bf16 (Q,K sections only)
    u16* vtb  = (u16*)(ws + 75497472);               // 16 MB  V^T bf16 (64bh x 64d x 2048s)
    u16* v2b  = (u16*)(ws + 92274688);               // 16 MB  vals2 bf16 (8192x1024)
    // scaled b_qkv lives in the v2b region: consumed by gemm_qkv, which
    // completes (same stream) before flash_attn overwrites v2b.
    float* bsc = (float*)(ws + 92274688);

    prep_inputs<<<6156, 256, 0, stream>>>(x, w_qkv, b_qkv, w_o, xb, wqb, wob, bsc);

    // qkv = x * w_qkv^T + b_qkv ; V section written transposed to vtb
    gemm_qkv<<<dim3(24, 64), 256, 0, stream>>>(xb, wqb, bsc, qkvb, vtb);

    // attention -> vals2 (bf16, quirky reshape layout)
    flash_attn<<<dim3(16, 64), 256, 0, stream>>>(qkvb, vtb, v2b);

    // out = vals2 * w_o^T + b_o   (M=8192, N=1024, K=1024), fp32 out
    gemm_out<<<dim3(16, 64), 256, 0, stream>>>(v2b, wob, b_o, out);
}

// Round 6
// 283.897 us; speedup vs baseline: 1.0240x; 1.0240x over previous
//
#include <hip/hip_runtime.h>
#include <stdint.h>
#include <stddef.h>

#define DEVINL __device__ __forceinline__

typedef unsigned short u16;
typedef unsigned int u32;
typedef __attribute__((ext_vector_type(8))) short short8;
typedef __attribute__((ext_vector_type(4))) float f32x4;
typedef __attribute__((ext_vector_type(4))) u32 u32x4;
typedef __attribute__((ext_vector_type(2))) u32 u32x2;

// log2(e)/8 : folded into W_q / b_q so flash's exp2 needs no multiply
#define QSCALE 0.18033688011112042f

// ---------- helpers ----------
DEVINL u16 f2bf(float f) {
    u32 u = __builtin_bit_cast(u32, f);
    u32 r = (u + 0x7fffu + ((u >> 16) & 1u)) >> 16;   // RNE
    return (u16)r;
}

DEVINL void gld_lds16(const void* g, void* l) {
    __builtin_amdgcn_global_load_lds(
        (__attribute__((address_space(1))) u32*)(uintptr_t)g,
        (__attribute__((address_space(3))) u32*)l, 16, 0, 0);
}

// pack two fp32 -> bf16x2 by truncation (bias cancels: denominator sums the same bf16 P)
DEVINL u32 pack_bf16_trunc(float lo, float hi) {
    return __builtin_amdgcn_perm(__builtin_bit_cast(u32, hi),
                                 __builtin_bit_cast(u32, lo), 0x07060302u);
}

// ---------- fused input prep: casts + scale folding, one launch ----------
__global__ void prep_inputs(const float* __restrict__ x, const float* __restrict__ wqkv,
                            const float* __restrict__ bqkv, const float* __restrict__ wo,
                            u16* __restrict__ xb, u16* __restrict__ wqb,
                            u16* __restrict__ wob, float* __restrict__ bsc) {
    int blk = blockIdx.x;
    if (blk < 6144) {
        const float* src; u16* dst; int base; bool qscale = false;
        if (blk < 4096)      { src = x;    dst = xb;  base = blk; }
        else if (blk < 5632) { src = wqkv; dst = wqb; base = blk - 4096; qscale = true; }
        else                 { src = wo;   dst = wob; base = blk - 5632; }
        int i = (base * 256 + threadIdx.x) * 8;
        float sc = 1.0f;
        if (qscale) { int row = i >> 10; if ((row % 192) < 64) sc = QSCALE; }
        float4 a = *(const float4*)(src + i);
        float4 c = *(const float4*)(src + i + 4);
        union { u16 s[8]; u32x4 v; } t;
        t.s[0] = f2bf(a.x * sc); t.s[1] = f2bf(a.y * sc); t.s[2] = f2bf(a.z * sc); t.s[3] = f2bf(a.w * sc);
        t.s[4] = f2bf(c.x * sc); t.s[5] = f2bf(c.y * sc); t.s[6] = f2bf(c.z * sc); t.s[7] = f2bf(c.w * sc);
        *(u32x4*)(dst + i) = t.v;
    } else {
        int i = (blk - 6144) * 256 + threadIdx.x;   // 0..3071
        float sc = ((i % 192) < 64) ? QSCALE : 1.0f;
        bsc[i] = bqkv[i] * sc;
    }
}

// ---------- QKV GEMM  qkv[M,3072] = x[M,K] * w_qkv[3072,K]^T + b ----------
// V-section columns written transposed straight to vt[bh][d][s].
__global__ void gemm_qkv(const u16* __restrict__ A, const u16* __restrict__ Bm,
                         const float* __restrict__ bias, u16* __restrict__ qkvb,
                         u16* __restrict__ vtb) {
    const int K = 1024, N = 3072;
    __shared__ u16 As[128 * 32];
    __shared__ u16 Bs[128 * 32];
    const int tid = threadIdx.x;
    const int lane = tid & 63;
    const int wv = tid >> 6, wr = wv >> 1, wc = wv & 1;
    const int l15 = lane & 15, quad = lane >> 4;
    const int m0 = blockIdx.y * 128, n0 = blockIdx.x * 128;

    f32x4 acc[4][4];
#pragma unroll
    for (int i = 0; i < 4; i++)
#pragma unroll
        for (int j = 0; j < 4; j++) acc[i][j] = (f32x4){0.f, 0.f, 0.f, 0.f};

    const u16* Ab = A + (size_t)m0 * K;
    const u16* Bb = Bm + (size_t)n0 * K;
    const int srow = tid >> 2;
    const int sc8 = (tid & 3) * 8;

    for (int k0 = 0; k0 < K; k0 += 32) {
#pragma unroll
        for (int i = 0; i < 2; i++) {
            int row = i * 64 + srow;
            gld_lds16(Ab + (size_t)row * K + k0 + sc8, (char*)As + (size_t)(i * 256 + tid) * 16);
            gld_lds16(Bb + (size_t)row * K + k0 + sc8, (char*)Bs + (size_t)(i * 256 + tid) * 16);
        }
        __syncthreads();
        short8 af[4], bf8[4];
#pragma unroll
        for (int mi = 0; mi < 4; mi++)
            af[mi] = *(const short8*)(As + (wr * 64 + mi * 16 + l15) * 32 + quad * 8);
#pragma unroll
        for (int ni = 0; ni < 4; ni++)
            bf8[ni] = *(const short8*)(Bs + (wc * 64 + ni * 16 + l15) * 32 + quad * 8);
#pragma unroll
        for (int mi = 0; mi < 4; mi++)
#pragma unroll
            for (int ni = 0; ni < 4; ni++)
                acc[mi][ni] = __builtin_amdgcn_mfma_f32_16x16x32_bf16(af[mi], bf8[ni], acc[mi][ni], 0, 0, 0);
        __syncthreads();
    }

#pragma unroll
    for (int mi = 0; mi < 4; mi++) {
        int row_b = m0 + wr * 64 + mi * 16 + quad * 4;
#pragma unroll
        for (int ni = 0; ni < 4; ni++) {
            int c0 = n0 + wc * 64 + ni * 16;          // group base (16-aligned)
            int sec0 = c0 % 192;                       // section offset, wave-uniform
            float bv = bias[c0 + l15];
            float v0 = acc[mi][ni][0] + bv;
            float v1 = acc[mi][ni][1] + bv;
            float v2 = acc[mi][ni][2] + bv;
            float v3 = acc[mi][ni][3] + bv;
            if (sec0 >= 128) {
                int hh = c0 / 192;
                int b = row_b >> 11;
                int s = row_b & 2047;
                int d = sec0 - 128 + l15;
                u32 lo = (u32)f2bf(v0) | ((u32)f2bf(v1) << 16);
                u32 hi = (u32)f2bf(v2) | ((u32)f2bf(v3) << 16);
                *(u32x2*)(vtb + ((size_t)((b * 16 + hh) * 64 + d)) * 2048 + s) = (u32x2){lo, hi};
            } else {
                int col = c0 + l15;
                qkvb[(size_t)(row_b + 0) * N + col] = f2bf(v0);
                qkvb[(size_t)(row_b + 1) * N + col] = f2bf(v1);
                qkvb[(size_t)(row_b + 2) * N + col] = f2bf(v2);
                qkvb[(size_t)(row_b + 3) * N + col] = f2bf(v3);
            }
        }
    }
}

// ---------- out GEMM  out[M,1024] = vals2[M,K] * w_o[1024,K]^T + b_o ----------
__global__ void gemm_out(const u16* __restrict__ A, const u16* __restrict__ Bm,
                         const float* __restrict__ bias, float* __restrict__ C) {
    const int K = 1024, N = 1024;
    __shared__ u16 As[128 * 32];
    __shared__ u16 Bs[64 * 32];
    const int tid = threadIdx.x;
    const int lane = tid & 63;
    const int wv = tid >> 6, wr = wv >> 1, wc = wv & 1;
    const int l15 = lane & 15, quad = lane >> 4;
    const int m0 = blockIdx.y * 128, n0 = blockIdx.x * 64;

    f32x4 acc[4][2];
#pragma unroll
    for (int i = 0; i < 4; i++)
#pragma unroll
        for (int j = 0; j < 2; j++) acc[i][j] = (f32x4){0.f, 0.f, 0.f, 0.f};

    const u16* Ab = A + (size_t)m0 * K;
    const u16* Bb = Bm + (size_t)n0 * K;
    const int srow = tid >> 2;
    const int sc8 = (tid & 3) * 8;

    for (int k0 = 0; k0 < K; k0 += 32) {
#pragma unroll
        for (int i = 0; i < 2; i++)
            gld_lds16(Ab + (size_t)(i * 64 + srow) * K + k0 + sc8, (char*)As + (size_t)(i * 256 + tid) * 16);
        gld_lds16(Bb + (size_t)srow * K + k0 + sc8, (char*)Bs + (size_t)tid * 16);
        __syncthreads();
        short8 af[4], bf8[2];
#pragma unroll
        for (int mi = 0; mi < 4; mi++)
            af[mi] = *(const short8*)(As + (wr * 64 + mi * 16 + l15) * 32 + quad * 8);
#pragma unroll
        for (int ni = 0; ni < 2; ni++)
            bf8[ni] = *(const short8*)(Bs + (wc * 32 + ni * 16 + l15) * 32 + quad * 8);
#pragma unroll
        for (int mi = 0; mi < 4; mi++)
#pragma unroll
            for (int ni = 0; ni < 2; ni++)
                acc[mi][ni] = __builtin_amdgcn_mfma_f32_16x16x32_bf16(af[mi], bf8[ni], acc[mi][ni], 0, 0, 0);
        __syncthreads();
    }

#pragma unroll
    for (int mi = 0; mi < 4; mi++) {
        int row_b = m0 + wr * 64 + mi * 16 + quad * 4;
#pragma unroll
        for (int ni = 0; ni < 2; ni++) {
            int col = n0 + wc * 32 + ni * 16 + l15;
            float bv = bias[col];
#pragma unroll
            for (int r = 0; r < 4; r++)
                C[(size_t)(row_b + r) * N + col] = acc[mi][ni][r] + bv;
        }
    }
}

// ---------- flash attention v5: r2 structure + register prefetch ----------
// K/V global loads for tile i+1 are issued AFTER the post-staging barrier,
// during tile i's compute (~1300 cyc) — the vmcnt(0) drain at the next
// barrier is then free. LDS 36 KB -> 4 blocks/CU.
__launch_bounds__(256, 4)
__global__ void flash_attn(const u16* __restrict__ qkv, const u16* __restrict__ vt,
                           u16* __restrict__ vals2) {
    __shared__ u16 Ks[64 * 72];      // 64 keys x 64 d
    __shared__ u16 Vts[64 * 72];     // 64 d   x 64 keys
    __shared__ u16 Ps[4][32 * 72];   // per-wave 32 q x 64 keys

    const int tid = threadIdx.x;
    const int lane = tid & 63, wv = tid >> 6;
    const int l15 = lane & 15, quad = lane >> 4;
    const int s0 = blockIdx.x * 128;
    const int bh = blockIdx.y, b = bh >> 4, h = bh & 15;

    // Q fragments in registers (q rows pre-scaled by log2e/8 at cast time)
    short8 qf[2][2];
    const u16* qbase = qkv + (size_t)(b * 2048 + s0 + wv * 32) * 3072 + h * 192;
#pragma unroll
    for (int qi = 0; qi < 2; qi++)
#pragma unroll
        for (int ks = 0; ks < 2; ks++)
            qf[qi][ks] = *(const short8*)(qbase + (size_t)(qi * 16 + l15) * 3072 + ks * 32 + quad * 8);

    f32x4 o_acc[2][4];
    f32x4 sum_acc[2];
#pragma unroll
    for (int qi = 0; qi < 2; qi++) {
        sum_acc[qi] = (f32x4){0.f, 0.f, 0.f, 0.f};
#pragma unroll
        for (int nd = 0; nd < 4; nd++) o_acc[qi][nd] = (f32x4){0.f, 0.f, 0.f, 0.f};
    }

    const u16* kg = qkv + (size_t)(b * 2048) * 3072 + h * 192 + 64;
    const u16* vg = vt + (size_t)bh * 64 * 2048;
    const int srow = tid >> 2;          // 0..63
    const int sc16 = (tid & 3) * 16;    // 0,16,32,48

    const short8 ones = (short8){0x3F80, 0x3F80, 0x3F80, 0x3F80, 0x3F80, 0x3F80, 0x3F80, 0x3F80};

    // prefetch tile 0 into registers
    u32x4 pk0 = *(const u32x4*)(kg + (size_t)srow * 3072 + sc16);
    u32x4 pk1 = *(const u32x4*)(kg + (size_t)srow * 3072 + sc16 + 8);
    u32x4 pv0 = *(const u32x4*)(vg + (size_t)srow * 2048 + sc16);
    u32x4 pv1 = *(const u32x4*)(vg + (size_t)srow * 2048 + sc16 + 8);

    for (int kb = 0; kb < 2048; kb += 64) {
        __syncthreads();
        // stage prefetched K (64 keys x 64 d) and Vt (64 d x 64 keys)
        *(u32x4*)(Ks + srow * 72 + sc16) = pk0;
        *(u32x4*)(Ks + srow * 72 + sc16 + 8) = pk1;
        *(u32x4*)(Vts + srow * 72 + sc16) = pv0;
        *(u32x4*)(Vts + srow * 72 + sc16 + 8) = pv1;
        __syncthreads();

        // issue next tile's global loads now — they complete under compute
        {
            int nkb = (kb + 64) & 2047;   // last iter wraps to 0 (harmless)
            pk0 = *(const u32x4*)(kg + (size_t)(nkb + srow) * 3072 + sc16);
            pk1 = *(const u32x4*)(kg + (size_t)(nkb + srow) * 3072 + sc16 + 8);
            pv0 = *(const u32x4*)(vg + (size_t)srow * 2048 + nkb + sc16);
            pv1 = *(const u32x4*)(vg + (size_t)srow * 2048 + nkb + sc16 + 8);
        }

        // S^T = K * Q^T : s_acc[ki][qi] -> key = ki*16+quad*4+r, q = qi*16+l15
        f32x4 s_acc[4][2];
#pragma unroll
        for (int ki = 0; ki < 4; ki++)
#pragma unroll
            for (int qi = 0; qi < 2; qi++) s_acc[ki][qi] = (f32x4){0.f, 0.f, 0.f, 0.f};
#pragma unroll
        for (int ki = 0; ki < 4; ki++) {
#pragma unroll
            for (int ks = 0; ks < 2; ks++) {
                short8 kf = *(const short8*)(Ks + (ki * 16 + l15) * 72 + ks * 32 + quad * 8);
#pragma unroll
                for (int qi = 0; qi < 2; qi++)
                    s_acc[ki][qi] = __builtin_amdgcn_mfma_f32_16x16x32_bf16(kf, qf[qi][ks], s_acc[ki][qi], 0, 0, 0);
            }
        }

        // P = exp2(S^T) -> truncate-pack bf16 -> per-wave LDS (A-layout rows [q][key])
#pragma unroll
        for (int ki = 0; ki < 4; ki++)
#pragma unroll
            for (int qi = 0; qi < 2; qi++) {
                float p0 = __builtin_amdgcn_exp2f(s_acc[ki][qi][0]);
                float p1 = __builtin_amdgcn_exp2f(s_acc[ki][qi][1]);
                float p2 = __builtin_amdgcn_exp2f(s_acc[ki][qi][2]);
                float p3 = __builtin_amdgcn_exp2f(s_acc[ki][qi][3]);
                u32x2 pk = (u32x2){pack_bf16_trunc(p0, p1), pack_bf16_trunc(p2, p3)};
                *(u32x2*)(Ps[wv] + (qi * 16 + l15) * 72 + ki * 16 + quad * 4) = pk;
            }

        // PV over 2 chunks of 32 keys; denominator via ones-column MFMA
#pragma unroll
        for (int c = 0; c < 2; c++) {
            short8 ap[2];
#pragma unroll
            for (int qi = 0; qi < 2; qi++)
                ap[qi] = *(const short8*)(Ps[wv] + (qi * 16 + l15) * 72 + c * 32 + quad * 8);
#pragma unroll
            for (int qi = 0; qi < 2; qi++)
                sum_acc[qi] = __builtin_amdgcn_mfma_f32_16x16x32_bf16(ap[qi], ones, sum_acc[qi], 0, 0, 0);
#pragma unroll
            for (int nd = 0; nd < 4; nd++) {
                short8 bv = *(const short8*)(Vts + (nd * 16 + l15) * 72 + c * 32 + quad * 8);
#pragma unroll
                for (int qi = 0; qi < 2; qi++)
                    o_acc[qi][nd] = __builtin_amdgcn_mfma_f32_16x16x32_bf16(ap[qi], bv, o_acc[qi][nd], 0, 0, 0);
            }
        }
    }

    // epilogue: normalize (sum broadcast across l15 by the ones-MFMA) and
    // write vals2 in the no-head-transpose reshape layout.
#pragma unroll
    for (int qi = 0; qi < 2; qi++) {
        f32x4 inv;
#pragma unroll
        for (int r = 0; r < 4; r++) inv[r] = 1.0f / sum_acc[qi][r];
#pragma unroll
        for (int nd = 0; nd < 4; nd++) {
            int d = nd * 16 + l15;
#pragma unroll
            for (int r = 0; r < 4; r++) {
                int s = s0 + wv * 32 + qi * 16 + quad * 4 + r;
                size_t row2 = (size_t)(b * 2048 + h * 128 + (s >> 4));
                int col2 = ((s & 15) << 6) + d;
                vals2[row2 * 1024 + col2] = f2bf(o_acc[qi][nd][r] * inv[r]);
            }
        }
    }
}

// ---------- launch ----------
extern "C" void kernel_launch(void* const* d_in, const int* in_sizes, int n_in,
                              void* d_out, int out_size, void* d_ws, size_t ws_size,
                              hipStream_t stream) {
    (void)in_sizes; (void)n_in; (void)out_size; (void)ws_size;
    const float* x      = (const float*)d_in[0];   // (4,2048,1024)
    const float* w_qkv  = (const float*)d_in[1];   // (3072,1024)
    const float* b_qkv  = (const float*)d_in[2];   // (3072,)
    const float* w_o    = (const float*)d_in[3];   // (1024,1024)
    const float* b_o    = (const float*)d_in[4];   // (1024,)
    float* out = (float*)d_out;

    char* ws = (char*)d_ws;
    u16* xb   = (u16*)(ws);                          // 16 MB  x bf16 (8192x1024)
    u16* wqb  = (u16*)(ws + 16777216);               // 6 MB   w_qkv bf16 (Q rows pre-scaled)
    u16* wob  = (u16*)(ws + 23068672);               // 2 MB   w_o bf16
    u16* qkvb = (u16*)(ws + 25165824);               // 48 MB  qkv bf16 (Q,K sections only)
    u16* vtb  = (u16*)(ws + 75497472);               // 16 MB  V^T bf16 (64bh x 64d x 2048s)
    u16* v2b  = (u16*)(ws + 92274688);               // 16 MB  vals2 bf16 (8192x1024)
    // scaled b_qkv lives in the v2b region: consumed by gemm_qkv, which
    // completes (same stream) before flash_attn overwrites v2b.
    float* bsc = (float*)(ws + 92274688);

    prep_inputs<<<6156, 256, 0, stream>>>(x, w_qkv, b_qkv, w_o, xb, wqb, wob, bsc);

    // qkv = x * w_qkv^T + b_qkv ; V section written transposed to vtb
    gemm_qkv<<<dim3(24, 64), 256, 0, stream>>>(xb, wqb, bsc, qkvb, vtb);

    // attention -> vals2 (bf16, quirky reshape layout)
    flash_attn<<<dim3(16, 64), 256, 0, stream>>>(qkvb, vtb, v2b);

    // out = vals2 * w_o^T + b_o   (M=8192, N=1024, K=1024), fp32 out
    gemm_out<<<dim3(16, 64), 256, 0, stream>>>(v2b, wob, b_o, out);
}

// Round 7
// 277.001 us; speedup vs baseline: 1.0495x; 1.0249x over previous
//
#include <hip/hip_runtime.h>
#include <stdint.h>
#include <stddef.h>

#define DEVINL __device__ __forceinline__

typedef unsigned short u16;
typedef unsigned int u32;
typedef __attribute__((ext_vector_type(8))) short short8;
typedef __attribute__((ext_vector_type(4))) float f32x4;
typedef __attribute__((ext_vector_type(4))) u32 u32x4;
typedef __attribute__((ext_vector_type(2))) u32 u32x2;

// log2(e)/8 : folded into W_q / b_q so flash's exp2 needs no multiply
#define QSCALE 0.18033688011112042f

// ---------- helpers ----------
DEVINL u16 f2bf(float f) {
    u32 u = __builtin_bit_cast(u32, f);
    u32 r = (u + 0x7fffu + ((u >> 16) & 1u)) >> 16;   // RNE
    return (u16)r;
}

DEVINL void gld_lds16(const void* g, void* l) {
    __builtin_amdgcn_global_load_lds(
        (__attribute__((address_space(1))) u32*)(uintptr_t)g,
        (__attribute__((address_space(3))) u32*)l, 16, 0, 0);
}

// pack two fp32 -> bf16x2 by truncation (bias cancels: denominator sums the same bf16 P)
DEVINL u32 pack_bf16_trunc(float lo, float hi) {
    return __builtin_amdgcn_perm(__builtin_bit_cast(u32, hi),
                                 __builtin_bit_cast(u32, lo), 0x07060302u);
}

// ---------- fused input prep: casts + scale folding, one launch ----------
__global__ void prep_inputs(const float* __restrict__ x, const float* __restrict__ wqkv,
                            const float* __restrict__ bqkv, const float* __restrict__ wo,
                            u16* __restrict__ xb, u16* __restrict__ wqb,
                            u16* __restrict__ wob, float* __restrict__ bsc) {
    int blk = blockIdx.x;
    if (blk < 6144) {
        const float* src; u16* dst; int base; bool qscale = false;
        if (blk < 4096)      { src = x;    dst = xb;  base = blk; }
        else if (blk < 5632) { src = wqkv; dst = wqb; base = blk - 4096; qscale = true; }
        else                 { src = wo;   dst = wob; base = blk - 5632; }
        int i = (base * 256 + threadIdx.x) * 8;
        float sc = 1.0f;
        if (qscale) { int row = i >> 10; if ((row % 192) < 64) sc = QSCALE; }
        float4 a = *(const float4*)(src + i);
        float4 c = *(const float4*)(src + i + 4);
        union { u16 s[8]; u32x4 v; } t;
        t.s[0] = f2bf(a.x * sc); t.s[1] = f2bf(a.y * sc); t.s[2] = f2bf(a.z * sc); t.s[3] = f2bf(a.w * sc);
        t.s[4] = f2bf(c.x * sc); t.s[5] = f2bf(c.y * sc); t.s[6] = f2bf(c.z * sc); t.s[7] = f2bf(c.w * sc);
        *(u32x4*)(dst + i) = t.v;
    } else {
        int i = (blk - 6144) * 256 + threadIdx.x;   // 0..3071
        float sc = ((i % 192) < 64) ? QSCALE : 1.0f;
        bsc[i] = bqkv[i] * sc;
    }
}

// ---------- QKV GEMM  qkv[M,3072] = x[M,K] * w_qkv[3072,K]^T + b ----------
// V-section columns written transposed straight to vt[bh][d][s].
__global__ void gemm_qkv(const u16* __restrict__ A, const u16* __restrict__ Bm,
                         const float* __restrict__ bias, u16* __restrict__ qkvb,
                         u16* __restrict__ vtb) {
    const int K = 1024, N = 3072;
    __shared__ u16 As[128 * 32];
    __shared__ u16 Bs[128 * 32];
    const int tid = threadIdx.x;
    const int lane = tid & 63;
    const int wv = tid >> 6, wr = wv >> 1, wc = wv & 1;
    const int l15 = lane & 15, quad = lane >> 4;
    const int m0 = blockIdx.y * 128, n0 = blockIdx.x * 128;

    f32x4 acc[4][4];
#pragma unroll
    for (int i = 0; i < 4; i++)
#pragma unroll
        for (int j = 0; j < 4; j++) acc[i][j] = (f32x4){0.f, 0.f, 0.f, 0.f};

    const u16* Ab = A + (size_t)m0 * K;
    const u16* Bb = Bm + (size_t)n0 * K;
    const int srow = tid >> 2;
    const int sc8 = (tid & 3) * 8;

    for (int k0 = 0; k0 < K; k0 += 32) {
#pragma unroll
        for (int i = 0; i < 2; i++) {
            int row = i * 64 + srow;
            gld_lds16(Ab + (size_t)row * K + k0 + sc8, (char*)As + (size_t)(i * 256 + tid) * 16);
            gld_lds16(Bb + (size_t)row * K + k0 + sc8, (char*)Bs + (size_t)(i * 256 + tid) * 16);
        }
        __syncthreads();
        short8 af[4], bf8[4];
#pragma unroll
        for (int mi = 0; mi < 4; mi++)
            af[mi] = *(const short8*)(As + (wr * 64 + mi * 16 + l15) * 32 + quad * 8);
#pragma unroll
        for (int ni = 0; ni < 4; ni++)
            bf8[ni] = *(const short8*)(Bs + (wc * 64 + ni * 16 + l15) * 32 + quad * 8);
#pragma unroll
        for (int mi = 0; mi < 4; mi++)
#pragma unroll
            for (int ni = 0; ni < 4; ni++)
                acc[mi][ni] = __builtin_amdgcn_mfma_f32_16x16x32_bf16(af[mi], bf8[ni], acc[mi][ni], 0, 0, 0);
        __syncthreads();
    }

#pragma unroll
    for (int mi = 0; mi < 4; mi++) {
        int row_b = m0 + wr * 64 + mi * 16 + quad * 4;
#pragma unroll
        for (int ni = 0; ni < 4; ni++) {
            int c0 = n0 + wc * 64 + ni * 16;          // group base (16-aligned)
            int sec0 = c0 % 192;                       // section offset, wave-uniform
            float bv = bias[c0 + l15];
            float v0 = acc[mi][ni][0] + bv;
            float v1 = acc[mi][ni][1] + bv;
            float v2 = acc[mi][ni][2] + bv;
            float v3 = acc[mi][ni][3] + bv;
            if (sec0 >= 128) {
                int hh = c0 / 192;
                int b = row_b >> 11;
                int s = row_b & 2047;
                int d = sec0 - 128 + l15;
                u32 lo = (u32)f2bf(v0) | ((u32)f2bf(v1) << 16);
                u32 hi = (u32)f2bf(v2) | ((u32)f2bf(v3) << 16);
                *(u32x2*)(vtb + ((size_t)((b * 16 + hh) * 64 + d)) * 2048 + s) = (u32x2){lo, hi};
            } else {
                int col = c0 + l15;
                qkvb[(size_t)(row_b + 0) * N + col] = f2bf(v0);
                qkvb[(size_t)(row_b + 1) * N + col] = f2bf(v1);
                qkvb[(size_t)(row_b + 2) * N + col] = f2bf(v2);
                qkvb[(size_t)(row_b + 3) * N + col] = f2bf(v3);
            }
        }
    }
}

// ---------- out GEMM  out[M,1024] = vals2[M,K] * w_o[1024,K]^T + b_o ----------
__global__ void gemm_out(const u16* __restrict__ A, const u16* __restrict__ Bm,
                         const float* __restrict__ bias, float* __restrict__ C) {
    const int K = 1024, N = 1024;
    __shared__ u16 As[128 * 32];
    __shared__ u16 Bs[64 * 32];
    const int tid = threadIdx.x;
    const int lane = tid & 63;
    const int wv = tid >> 6, wr = wv >> 1, wc = wv & 1;
    const int l15 = lane & 15, quad = lane >> 4;
    const int m0 = blockIdx.y * 128, n0 = blockIdx.x * 64;

    f32x4 acc[4][2];
#pragma unroll
    for (int i = 0; i < 4; i++)
#pragma unroll
        for (int j = 0; j < 2; j++) acc[i][j] = (f32x4){0.f, 0.f, 0.f, 0.f};

    const u16* Ab = A + (size_t)m0 * K;
    const u16* Bb = Bm + (size_t)n0 * K;
    const int srow = tid >> 2;
    const int sc8 = (tid & 3) * 8;

    for (int k0 = 0; k0 < K; k0 += 32) {
#pragma unroll
        for (int i = 0; i < 2; i++)
            gld_lds16(Ab + (size_t)(i * 64 + srow) * K + k0 + sc8, (char*)As + (size_t)(i * 256 + tid) * 16);
        gld_lds16(Bb + (size_t)srow * K + k0 + sc8, (char*)Bs + (size_t)tid * 16);
        __syncthreads();
        short8 af[4], bf8[2];
#pragma unroll
        for (int mi = 0; mi < 4; mi++)
            af[mi] = *(const short8*)(As + (wr * 64 + mi * 16 + l15) * 32 + quad * 8);
#pragma unroll
        for (int ni = 0; ni < 2; ni++)
            bf8[ni] = *(const short8*)(Bs + (wc * 32 + ni * 16 + l15) * 32 + quad * 8);
#pragma unroll
        for (int mi = 0; mi < 4; mi++)
#pragma unroll
            for (int ni = 0; ni < 2; ni++)
                acc[mi][ni] = __builtin_amdgcn_mfma_f32_16x16x32_bf16(af[mi], bf8[ni], acc[mi][ni], 0, 0, 0);
        __syncthreads();
    }

#pragma unroll
    for (int mi = 0; mi < 4; mi++) {
        int row_b = m0 + wr * 64 + mi * 16 + quad * 4;
#pragma unroll
        for (int ni = 0; ni < 2; ni++) {
            int col = n0 + wc * 32 + ni * 16 + l15;
            float bv = bias[col];
#pragma unroll
            for (int r = 0; r < 4; r++)
                C[(size_t)(row_b + r) * N + col] = acc[mi][ni][r] + bv;
        }
    }
}

// ---------- flash attention v6: P stays in registers ----------
// S^T = K*Q^T (key=quad*4+r, q=l15). P^T converted in-register to the MFMA
// B-operand layout with v_permlane32/16_swap (4x4 quad<->reg transpose), then
// O^T = V^T * P^T. No P LDS round-trip; LDS = K+V tiles only (18 KB).
// Denominator via ones-as-A MFMA (broadcast over rows). Epilogue: O^T C-layout
// gives 4 consecutive d per lane -> coalesced u32x2 stores.
__launch_bounds__(256, 4)
__global__ void flash_attn(const u16* __restrict__ qkv, const u16* __restrict__ vt,
                           u16* __restrict__ vals2) {
    __shared__ u16 Ks[64 * 72];      // 64 keys x 64 d
    __shared__ u16 Vts[64 * 72];     // 64 d   x 64 keys

    const int tid = threadIdx.x;
    const int lane = tid & 63, wv = tid >> 6;
    const int l15 = lane & 15, quad = lane >> 4;
    const int s0 = blockIdx.x * 128;
    const int bh = blockIdx.y, b = bh >> 4, h = bh & 15;

    // Q fragments in registers (q rows pre-scaled by log2e/8 at cast time)
    short8 qf[2][2];
    const u16* qbase = qkv + (size_t)(b * 2048 + s0 + wv * 32) * 3072 + h * 192;
#pragma unroll
    for (int qi = 0; qi < 2; qi++)
#pragma unroll
        for (int ks = 0; ks < 2; ks++)
            qf[qi][ks] = *(const short8*)(qbase + (size_t)(qi * 16 + l15) * 3072 + ks * 32 + quad * 8);

    f32x4 o_acc[2][4];     // O^T: d = nd*16 + quad*4 + r, q = l15
    f32x4 sum_acc[2];
#pragma unroll
    for (int qi = 0; qi < 2; qi++) {
        sum_acc[qi] = (f32x4){0.f, 0.f, 0.f, 0.f};
#pragma unroll
        for (int nd = 0; nd < 4; nd++) o_acc[qi][nd] = (f32x4){0.f, 0.f, 0.f, 0.f};
    }

    const u16* kg = qkv + (size_t)(b * 2048) * 3072 + h * 192 + 64;
    const u16* vg = vt + (size_t)bh * 64 * 2048;
    const int srow = tid >> 2;          // 0..63
    const int sc16 = (tid & 3) * 16;    // 0,16,32,48

    const short8 ones = (short8){0x3F80, 0x3F80, 0x3F80, 0x3F80, 0x3F80, 0x3F80, 0x3F80, 0x3F80};

    // prefetch tile 0 into registers
    u32x4 pk0 = *(const u32x4*)(kg + (size_t)srow * 3072 + sc16);
    u32x4 pk1 = *(const u32x4*)(kg + (size_t)srow * 3072 + sc16 + 8);
    u32x4 pv0 = *(const u32x4*)(vg + (size_t)srow * 2048 + sc16);
    u32x4 pv1 = *(const u32x4*)(vg + (size_t)srow * 2048 + sc16 + 8);

    for (int kb = 0; kb < 2048; kb += 64) {
        __syncthreads();
        *(u32x4*)(Ks + srow * 72 + sc16) = pk0;
        *(u32x4*)(Ks + srow * 72 + sc16 + 8) = pk1;
        *(u32x4*)(Vts + srow * 72 + sc16) = pv0;
        *(u32x4*)(Vts + srow * 72 + sc16 + 8) = pv1;
        __syncthreads();

        // issue next tile's global loads now — complete under compute
        {
            int nkb = (kb + 64) & 2047;
            pk0 = *(const u32x4*)(kg + (size_t)(nkb + srow) * 3072 + sc16);
            pk1 = *(const u32x4*)(kg + (size_t)(nkb + srow) * 3072 + sc16 + 8);
            pv0 = *(const u32x4*)(vg + (size_t)srow * 2048 + nkb + sc16);
            pv1 = *(const u32x4*)(vg + (size_t)srow * 2048 + nkb + sc16 + 8);
        }

        // S^T = K * Q^T : s_acc[ki][qi] -> key = ki*16+quad*4+r, q = qi*16+l15
        f32x4 s_acc[4][2];
#pragma unroll
        for (int ki = 0; ki < 4; ki++)
#pragma unroll
            for (int qi = 0; qi < 2; qi++) s_acc[ki][qi] = (f32x4){0.f, 0.f, 0.f, 0.f};
#pragma unroll
        for (int ki = 0; ki < 4; ki++) {
#pragma unroll
            for (int ks = 0; ks < 2; ks++) {
                short8 kf = *(const short8*)(Ks + (ki * 16 + l15) * 72 + ks * 32 + quad * 8);
#pragma unroll
                for (int qi = 0; qi < 2; qi++)
                    s_acc[ki][qi] = __builtin_amdgcn_mfma_f32_16x16x32_bf16(kf, qf[qi][ks], s_acc[ki][qi], 0, 0, 0);
            }
        }

        // P = exp2(S^T), truncate-packed: Xp=keys quad*4+{0,1}, Yp=+{2,3}
        u32 Xp[4][2], Yp[4][2];
#pragma unroll
        for (int ki = 0; ki < 4; ki++)
#pragma unroll
            for (int qi = 0; qi < 2; qi++) {
                float p0 = __builtin_amdgcn_exp2f(s_acc[ki][qi][0]);
                float p1 = __builtin_amdgcn_exp2f(s_acc[ki][qi][1]);
                float p2 = __builtin_amdgcn_exp2f(s_acc[ki][qi][2]);
                float p3 = __builtin_amdgcn_exp2f(s_acc[ki][qi][3]);
                Xp[ki][qi] = pack_bf16_trunc(p0, p1);
                Yp[ki][qi] = pack_bf16_trunc(p2, p3);
            }

        // PV over 2 chunks of 32 keys; P^T -> B-layout via quad<->reg transpose
#pragma unroll
        for (int c = 0; c < 2; c++) {
            short8 vf[4];
#pragma unroll
            for (int nd = 0; nd < 4; nd++)
                vf[nd] = *(const short8*)(Vts + (nd * 16 + l15) * 72 + c * 32 + quad * 8);
#pragma unroll
            for (int qi = 0; qi < 2; qi++) {
                u32 b0 = Xp[2 * c + 0][qi];
                u32 b1 = Yp[2 * c + 0][qi];
                u32 b2 = Xp[2 * c + 1][qi];
                u32 b3 = Yp[2 * c + 1][qi];
                // swap lane bit5 <-> reg bit (ki), then lane bit4 <-> that bit
                asm volatile("v_permlane32_swap_b32 %0, %1" : "+v"(b0), "+v"(b2));
                asm volatile("v_permlane32_swap_b32 %0, %1" : "+v"(b1), "+v"(b3));
                asm volatile("v_permlane16_swap_b32 %0, %1" : "+v"(b0), "+v"(b2));
                asm volatile("v_permlane16_swap_b32 %0, %1" : "+v"(b1), "+v"(b3));
                short8 pb = __builtin_bit_cast(short8, (u32x4){b0, b1, b2, b3});
                sum_acc[qi] = __builtin_amdgcn_mfma_f32_16x16x32_bf16(ones, pb, sum_acc[qi], 0, 0, 0);
#pragma unroll
                for (int nd = 0; nd < 4; nd++)
                    o_acc[qi][nd] = __builtin_amdgcn_mfma_f32_16x16x32_bf16(vf[nd], pb, o_acc[qi][nd], 0, 0, 0);
            }
        }
    }

    // epilogue: O^T layout -> 4 consecutive d per (qi,nd); sum broadcast over
    // rows so inv is one scalar per lane. s>>4 is wave-uniform, s&15 = l15.
#pragma unroll
    for (int qi = 0; qi < 2; qi++) {
        float inv = 1.0f / sum_acc[qi][0];
        int row2 = b * 2048 + h * 128 + ((s0 + wv * 32 + qi * 16) >> 4);
        u16* base = vals2 + (size_t)row2 * 1024 + l15 * 64 + quad * 4;
#pragma unroll
        for (int nd = 0; nd < 4; nd++) {
            float o0 = o_acc[qi][nd][0] * inv;
            float o1 = o_acc[qi][nd][1] * inv;
            float o2 = o_acc[qi][nd][2] * inv;
            float o3 = o_acc[qi][nd][3] * inv;
            u32 lo = (u32)f2bf(o0) | ((u32)f2bf(o1) << 16);
            u32 hi = (u32)f2bf(o2) | ((u32)f2bf(o3) << 16);
            *(u32x2*)(base + nd * 16) = (u32x2){lo, hi};
        }
    }
}

// ---------- launch ----------
extern "C" void kernel_launch(void* const* d_in, const int* in_sizes, int n_in,
                              void* d_out, int out_size, void* d_ws, size_t ws_size,
                              hipStream_t stream) {
    (void)in_sizes; (void)n_in; (void)out_size; (void)ws_size;
    const float* x      = (const float*)d_in[0];   // (4,2048,1024)
    const float* w_qkv  = (const float*)d_in[1];   // (3072,1024)
    const float* b_qkv  = (const float*)d_in[2];   // (3072,)
    const float* w_o    = (const float*)d_in[3];   // (1024,1024)
    const float* b_o    = (const float*)d_in[4];   // (1024,)
    float* out = (float*)d_out;

    char* ws = (char*)d_ws;
    u16* xb   = (u16*)(ws);                          // 16 MB  x bf16 (8192x1024)
    u16* wqb  = (u16*)(ws + 16777216);               // 6 MB   w_qkv bf16 (Q rows pre-scaled)
    u16* wob  = (u16*)(ws + 23068672);               // 2 MB   w_o bf16
    u16* qkvb = (u16*)(ws + 25165824);               // 48 MB  qkv bf16 (Q,K sections only)
    u16* vtb  = (u16*)(ws + 75497472);               // 16 MB  V^T bf16 (64bh x 64d x 2048s)
    u16* v2b  = (u16*)(ws + 92274688);               // 16 MB  vals2 bf16 (8192x1024)
    // scaled b_qkv lives in the v2b region: consumed by gemm_qkv, which
    // completes (same stream) before flash_attn overwrites v2b.
    float* bsc = (float*)(ws + 92274688);

    prep_inputs<<<6156, 256, 0, stream>>>(x, w_qkv, b_qkv, w_o, xb, wqb, wob, bsc);

    // qkv = x * w_qkv^T + b_qkv ; V section written transposed to vtb
    gemm_qkv<<<dim3(24, 64), 256, 0, stream>>>(xb, wqb, bsc, qkvb, vtb);

    // attention -> vals2 (bf16, quirky reshape layout)
    flash_attn<<<dim3(16, 64), 256, 0, stream>>>(qkvb, vtb, v2b);

    // out = vals2 * w_o^T + b_o   (M=8192, N=1024, K=1024), fp32 out
    gemm_out<<<dim3(16, 64), 256, 0, stream>>>(v2b, wob, b_o, out);
}